// Round 1
// baseline (80.393 us; speedup 1.0000x reference)
//
#include <hip/hip_runtime.h>

#define NB    512
#define NC    128
#define HW    49
#define FEAT  21609   // 21*21*7*7
#define NPAIR 625
#define CHW   6272    // NC*HW
#define NVEC4 1568    // CHW/4

// 25 same-parity (i,i2) pairs for i,i2 in [0,7)
__constant__ int c_pi[25]  = {0,0,0,0, 1,1,1, 2,2,2,2, 3,3,3, 4,4,4,4, 5,5,5, 6,6,6,6};
__constant__ int c_pi2[25] = {0,2,4,6, 1,3,5, 0,2,4,6, 1,3,5, 0,2,4,6, 1,3,5, 0,2,4,6};

__global__ __launch_bounds__(256) void corr_head_kernel(
    const float* __restrict__ patch1,
    const float* __restrict__ patch2,
    const float* __restrict__ w_bbox,
    const float* __restrict__ b_bbox,
    float* __restrict__ out)
{
    __shared__ float  s1[CHW];        // patch1[b]  [c][ij], 25088 B
    __shared__ float  s2[CHW];        // patch2[b]  [c][kl], 25088 B
    __shared__ float4 s_w[NPAIR];     // 4 head weights per nonzero pair, 10000 B
    __shared__ int    s_pair[NPAIR];  // (ij<<8)|kl, 2500 B
    __shared__ float  s_red[16];

    const int tid = threadIdx.x;
    const int b   = blockIdx.x;

    // ---- stage patch1[b], patch2[b] into LDS (float4, coalesced) ----
    const float4* g1 = (const float4*)(patch1 + (size_t)b * CHW);
    const float4* g2 = (const float4*)(patch2 + (size_t)b * CHW);
    float4* v1 = (float4*)s1;
    float4* v2 = (float4*)s2;
    for (int t = tid; t < NVEC4; t += 256) {
        v1[t] = g1[t];
        v2[t] = g2[t];
    }

    // ---- build compact nonzero-pair table (625 entries) ----
    // pair n -> (i,i2) from n/25, (j,j2) from n%25; weight w_bbox[o, ((p*21+q)*7+i)*7+j]
    for (int n = tid; n < NPAIR; n += 256) {
        int a  = n / 25;
        int bb = n - a * 25;
        int i  = c_pi[a],  i2 = c_pi2[a];
        int j  = c_pi[bb], j2 = c_pi2[bb];
        int p  = 10 + ((i2 - i) >> 1);
        int q  = 10 + ((j2 - j) >> 1);
        int feat = ((p * 21 + q) * 7 + i) * 7 + j;
        s_pair[n] = ((i * 7 + j) << 8) | (i2 * 7 + j2);
        s_w[n] = make_float4(w_bbox[feat],
                             w_bbox[FEAT + feat],
                             w_bbox[2 * FEAT + feat],
                             w_bbox[3 * FEAT + feat]);
    }
    __syncthreads();

    // ---- 625 dots of length 128, weighted into 4 accumulators ----
    float a0 = 0.f, a1 = 0.f, a2 = 0.f, a3 = 0.f;
    for (int n = tid; n < NPAIR; n += 256) {
        int pr = s_pair[n];
        int ij = pr >> 8;
        int kl = pr & 255;
        const float* p1c = s1 + ij;
        const float* p2c = s2 + kl;
        float dot = 0.f;
        #pragma unroll 16
        for (int c = 0; c < NC; ++c)
            dot += p1c[c * HW] * p2c[c * HW];
        float4 w = s_w[n];
        a0 += dot * w.x;
        a1 += dot * w.y;
        a2 += dot * w.z;
        a3 += dot * w.w;
    }

    // ---- reduce 256 threads -> 4 outputs ----
    for (int off = 32; off > 0; off >>= 1) {
        a0 += __shfl_down(a0, off, 64);
        a1 += __shfl_down(a1, off, 64);
        a2 += __shfl_down(a2, off, 64);
        a3 += __shfl_down(a3, off, 64);
    }
    int wave = tid >> 6;
    if ((tid & 63) == 0) {
        s_red[wave * 4 + 0] = a0;
        s_red[wave * 4 + 1] = a1;
        s_red[wave * 4 + 2] = a2;
        s_red[wave * 4 + 3] = a3;
    }
    __syncthreads();
    if (tid < 4) {
        float r = s_red[tid] + s_red[4 + tid] + s_red[8 + tid] + s_red[12 + tid];
        out[b * 4 + tid] = r + b_bbox[tid];
    }
}

extern "C" void kernel_launch(void* const* d_in, const int* in_sizes, int n_in,
                              void* d_out, int out_size, void* d_ws, size_t ws_size,
                              hipStream_t stream) {
    const float* patch1 = (const float*)d_in[0];
    const float* patch2 = (const float*)d_in[1];
    const float* w_bbox = (const float*)d_in[2];
    const float* b_bbox = (const float*)d_in[3];
    float* out = (float*)d_out;
    corr_head_kernel<<<dim3(NB), dim3(256), 0, stream>>>(patch1, patch2, w_bbox, b_bbox, out);
}